// Round 2
// baseline (279.238 us; speedup 1.0000x reference)
//
#include <hip/hip_runtime.h>
#include <stdint.h>

// Problem constants
#define BB 4
#define SS 2048
#define PP 8
#define FIN 1024
#define FOUT 1024
#define MROWS (BB*SS)          // 8192 rows per group
#define ROWSTRIDE (PP*FIN)     // 8192 floats between consecutive (b,s) rows
#define OROWSTRIDE (PP*FOUT)

// Tile config
#define BM 128
#define BN 128
#define BK 64
#define NKT (FIN/BK)           // 16 K-steps

typedef float fx4 __attribute__((ext_vector_type(4)));
typedef short sv8 __attribute__((ext_vector_type(8)));   // 8 bf16 as shorts (MFMA frag)

union BCvt { sv8 s; __bf16 b[8]; };

__device__ __forceinline__ unsigned short bfbits(float f) {
    union { __bf16 b; unsigned short u; } c; c.b = (__bf16)f; return c.u;
}

__device__ __forceinline__ sv8 cvt8(fx4 lo, fx4 hi) {
    BCvt u;
#pragma unroll
    for (int i = 0; i < 4; ++i) { u.b[i] = (__bf16)lo[i]; u.b[i + 4] = (__bf16)hi[i]; }
    return u.s;
}

// ---------------------------------------------------------------------------
// Prepass: W [P][K][N] fp32 -> Wt tiled+swizzled bf16 (16.8 MB into d_ws).
// Wt layout: tile (p, nt, kt) = contiguous 16 KB = exact LDS image:
//   for n in [0,128), kg in [0,8): 8 k-contiguous bf16 at
//   byte offset n*128 + ((kg*16) ^ ((n&7)<<4))
// so the GEMM stages B with linear global_load_lds (swizzle pre-baked).
// ---------------------------------------------------------------------------
__global__ __launch_bounds__(256) void wtrans(const float* __restrict__ w,
                                              unsigned short* __restrict__ wt) {
    __shared__ unsigned short L[64 * 130];   // [k][n], padded
    const int bid = blockIdx.x;              // 8*8*16 = 1024 blocks
    const int p  = bid >> 7;
    const int nt = (bid >> 4) & 7;
    const int kt = bid & 15;
    const int k0 = kt * 64, n0 = nt * 128;
    const int t = threadIdx.x;

    // load: 64 k-rows x 128 n, coalesced over n
    const int nf = t & 31, kl = t >> 5;
#pragma unroll
    for (int rr = 0; rr < 8; ++rr) {
        const int k = rr * 8 + kl;
        fx4 v = *(const fx4*)(w + (size_t)p * (FIN*FOUT) + (k0 + k) * FOUT + n0 + nf * 4);
        unsigned short* d = &L[k * 130 + nf * 4];
        d[0] = bfbits(v[0]); d[1] = bfbits(v[1]); d[2] = bfbits(v[2]); d[3] = bfbits(v[3]);
    }
    __syncthreads();

    // scatter into swizzled tile image
    unsigned short* tile = wt + (size_t)bid * 8192;
    const int n = t & 127, khalf = t >> 7;
#pragma unroll
    for (int rr = 0; rr < 4; ++rr) {
        const int kg = khalf * 4 + rr;
        union { sv8 s; unsigned short us[8]; } u;
#pragma unroll
        for (int e = 0; e < 8; ++e) u.us[e] = L[(kg * 8 + e) * 130 + n];
        const int byte_ = n * 128 + ((kg * 16) ^ ((n & 7) << 4));
        *(sv8*)((char*)tile + byte_) = u.s;
    }
}

// ---------------------------------------------------------------------------
// Grouped GEMM, fully double-buffered, 1 barrier per K-step.
// TIER 1: B via global_load_lds from pre-tiled Wt. TIER 0: B reg-staged fp32.
// ---------------------------------------------------------------------------

#define LOADA(kt, rset) do {                                                          \
    _Pragma("unroll")                                                                 \
    for (int rr = 0; rr < 4; ++rr) {                                                  \
        const float* s_ = aptr + rr * (32 * ROWSTRIDE) + (kt) * BK;                   \
        rset[rr][0] = *(const fx4*)s_;                                                \
        rset[rr][1] = *(const fx4*)(s_ + 4);                                          \
    }                                                                                 \
} while (0)

#define STOREA(rset, buf) do {                                                        \
    _Pragma("unroll")                                                                 \
    for (int rr = 0; rr < 4; ++rr) {                                                  \
        const int m_ = a_m + rr * 32;                                                 \
        const int byte_ = m_ * 128 + ((a_kg * 16) ^ ((m_ & 7) << 4));                 \
        *(sv8*)(ldsA[buf] + byte_) = cvt8(rset[rr][0], rset[rr][1]);                  \
    }                                                                                 \
} while (0)

// B half: 16 KB tile, 4 chunks of 4 KB; per chunk each wave DMAs 1 KB.
#define GLOADB(kt, buf) do {                                                          \
    const char* gb_ = (const char*)btile + (kt) * 16384;                              \
    _Pragma("unroll")                                                                 \
    for (int c_ = 0; c_ < 4; ++c_) {                                                  \
        __builtin_amdgcn_global_load_lds(                                             \
            (const __attribute__((address_space(1))) void*)(gb_ + c_ * 4096 + tid * 16), \
            (__attribute__((address_space(3))) void*)(ldsB[buf] + c_ * 4096 + wv * 1024), \
            16, 0, 0);                                                                \
    }                                                                                 \
} while (0)

#define LOADB0(kt, rset) do {                                                         \
    _Pragma("unroll")                                                                 \
    for (int rr = 0; rr < 4; ++rr) {                                                  \
        const int kg_ = b0_kg + rr * 2;                                               \
        _Pragma("unroll")                                                             \
        for (int e = 0; e < 8; ++e)                                                   \
            rset[rr][e] = w[(size_t)p * (FIN*FOUT) + ((kt) * BK + kg_ * 8 + e) * FOUT \
                            + n0 + b0_n];                                             \
    }                                                                                 \
} while (0)

#define STOREB0(rset, buf) do {                                                       \
    _Pragma("unroll")                                                                 \
    for (int rr = 0; rr < 4; ++rr) {                                                  \
        const int kg_ = b0_kg + rr * 2;                                               \
        const int byte_ = b0_n * 128 + ((kg_ * 16) ^ ((b0_n & 7) << 4));              \
        BCvt u_;                                                                      \
        _Pragma("unroll")                                                             \
        for (int e = 0; e < 8; ++e) u_.b[e] = (__bf16)rset[rr][e];                    \
        *(sv8*)(ldsB[buf] + byte_) = u_.s;                                            \
    }                                                                                 \
} while (0)

#define MFMA_PHASE(buf) do {                                                          \
    const char* Ab_ = ldsA[buf]; const char* Bb_ = ldsB[buf];                         \
    _Pragma("unroll")                                                                 \
    for (int ks = 0; ks < 2; ++ks) {                                                  \
        sv8 af_[4], bfr_[4];                                                          \
        _Pragma("unroll")                                                             \
        for (int f = 0; f < 4; ++f) {                                                 \
            const int row_ = wm * 64 + f * 16 + (lane & 15);                          \
            af_[f] = *(const sv8*)(Ab_ + row_ * 128 +                                 \
                       ((ks * 64 + (lane >> 4) * 16) ^ ((row_ & 7) << 4)));           \
        }                                                                             \
        _Pragma("unroll")                                                             \
        for (int f = 0; f < 4; ++f) {                                                 \
            const int row_ = wn * 64 + f * 16 + (lane & 15);                          \
            bfr_[f] = *(const sv8*)(Bb_ + row_ * 128 +                                \
                       ((ks * 64 + (lane >> 4) * 16) ^ ((row_ & 7) << 4)));           \
        }                                                                             \
        _Pragma("unroll")                                                             \
        for (int i = 0; i < 4; ++i)                                                   \
            _Pragma("unroll")                                                         \
            for (int j = 0; j < 4; ++j)                                               \
                acc[i][j] = __builtin_amdgcn_mfma_f32_16x16x32_bf16(                  \
                                af_[i], bfr_[j], acc[i][j], 0, 0, 0);                 \
    }                                                                                 \
} while (0)

template <int TIER>
__global__ __launch_bounds__(256, 2)
void pd_gemm(const float* __restrict__ x, const float* __restrict__ w,
             const unsigned short* __restrict__ wt, const float* __restrict__ bias,
             float* __restrict__ out) {
    __shared__ __align__(16) char ldsA[2][BM * BK * 2];   // 2 x 16 KB, swizzled bf16
    __shared__ __align__(16) char ldsB[2][BN * BK * 2];   // 2 x 16 KB

    const int tid = threadIdx.x;
    const int lane = tid & 63;
    const int wv = tid >> 6;           // 4 waves: 2x2 over the 128x128 tile
    const int wm = wv >> 1, wn = wv & 1;

    // XCD swizzle: 4096 blocks, 8 XCDs, 512 blocks/XCD == exactly one group.
    const int bid = blockIdx.x;
    const int swz = (bid & 7) * 512 + (bid >> 3);
    const int p   = swz >> 9;          // group == XCD -> Wt_p (2.1 MB) L2-resident
    const int wrk = swz & 511;
    const int n0  = (wrk & 7) * BN;    // n fastest: 8 consecutive blocks share A-panel
    const int m0  = (wrk >> 3) * BM;

    const int a_kg = tid & 7, a_m = tid >> 3;
    const float* aptr = x + (size_t)(m0 + a_m) * ROWSTRIDE + p * FIN + a_kg * 8;
    const unsigned short* btile = wt + (size_t)((p * 8 + (n0 >> 7)) * 16) * 8192;
    const int b0_n = (tid & 63) + ((wv & 1) << 6);
    const int b0_kg = wv >> 1;

    fx4 acc[4][4];
#pragma unroll
    for (int i = 0; i < 4; ++i)
#pragma unroll
        for (int j = 0; j < 4; ++j) acc[i][j] = (fx4)0.0f;

    fx4 rA0[4][2], rA1[4][2];

    if constexpr (TIER == 1) {
        // Prologue: stage tile 0, prefetch A(1)
        LOADA(0, rA0);
        STOREA(rA0, 0);          // compiler waits rA0 loads via vmcnt
        GLOADB(0, 0);
        LOADA(1, rA1);
        __syncthreads();         // drains: B(0) in LDS, rA1 in regs

#pragma unroll 1
        for (int kk = 0; kk < NKT / 2; ++kk) {
            const int kt = 2 * kk;
            // step kt (cur=0): stage tile kt+1 into buf 1, prefetch A(kt+2)
            if (kt + 1 < NKT) { GLOADB(kt + 1, 1); STOREA(rA1, 1); }
            if (kt + 2 < NKT) LOADA(kt + 2, rA0);
            MFMA_PHASE(0);
            __syncthreads();
            // step kt+1 (cur=1): stage tile kt+2 into buf 0, prefetch A(kt+3)
            if (kt + 2 < NKT) { GLOADB(kt + 2, 0); STOREA(rA0, 0); }
            if (kt + 3 < NKT) LOADA(kt + 3, rA1);
            MFMA_PHASE(1);
            __syncthreads();
        }
    } else {
        float rB0f[4][8], rB1f[4][8];
        LOADA(0, rA0); LOADB0(0, rB0f);
        STOREA(rA0, 0); STOREB0(rB0f, 0);
        LOADA(1, rA1); LOADB0(1, rB1f);
        __syncthreads();
#pragma unroll 1
        for (int kk = 0; kk < NKT / 2; ++kk) {
            const int kt = 2 * kk;
            if (kt + 1 < NKT) { STOREB0(rB1f, 1); STOREA(rA1, 1); }
            if (kt + 2 < NKT) { LOADA(kt + 2, rA0); LOADB0(kt + 2, rB0f); }
            MFMA_PHASE(0);
            __syncthreads();
            if (kt + 2 < NKT) { STOREB0(rB0f, 0); STOREA(rA0, 0); }
            if (kt + 3 < NKT) { LOADA(kt + 3, rA1); LOADB0(kt + 3, rB1f); }
            MFMA_PHASE(1);
            __syncthreads();
        }
    }

    // Epilogue: C/D layout col = lane&15, row = (lane>>4)*4 + j (m89/m91-verified)
    const float* bs = bias + p * FOUT;
#pragma unroll
    for (int fn = 0; fn < 4; ++fn) {
        const int col = n0 + wn * 64 + fn * 16 + (lane & 15);
        const float bv = bs[col];
#pragma unroll
        for (int fm = 0; fm < 4; ++fm) {
            const int row = m0 + wm * 64 + fm * 16 + (lane >> 4) * 4;
            float* o = out + (size_t)row * OROWSTRIDE + p * FOUT + col;
#pragma unroll
            for (int j = 0; j < 4; ++j)
                o[j * OROWSTRIDE] = acc[fm][fn][j] + bv;
        }
    }
}

extern "C" void kernel_launch(void* const* d_in, const int* in_sizes, int n_in,
                              void* d_out, int out_size, void* d_ws, size_t ws_size,
                              hipStream_t stream) {
    const float* x    = (const float*)d_in[0];
    const float* w    = (const float*)d_in[1];
    const float* bias = (const float*)d_in[2];
    float* out = (float*)d_out;

    const size_t WT_BYTES = (size_t)PP * FIN * FOUT * sizeof(unsigned short);  // 16.8 MB
    const int nblk = PP * (MROWS / BM) * (FOUT / BN);   // 8*64*8 = 4096

    if (ws_size >= WT_BYTES) {
        unsigned short* wt = (unsigned short*)d_ws;
        wtrans<<<dim3(1024), dim3(256), 0, stream>>>(w, wt);
        pd_gemm<1><<<dim3(nblk), dim3(256), 0, stream>>>(x, w, wt, bias, out);
    } else {
        pd_gemm<0><<<dim3(nblk), dim3(256), 0, stream>>>(x, w, nullptr, bias, out);
    }
}

// Round 3
// 228.396 us; speedup vs baseline: 1.2226x; 1.2226x over previous
//
#include <hip/hip_runtime.h>
#include <stdint.h>

// Problem constants
#define BB 4
#define SS 2048
#define PP 8
#define FIN 1024
#define FOUT 1024
#define MROWS (BB*SS)          // 8192 rows per group
#define ROWSTRIDE (PP*FIN)     // 8192 floats between consecutive (b,s) rows
#define OROWSTRIDE (PP*FOUT)

// Tile config: 256x256, BK=64, 512 threads (8 waves as 2x4)
#define BM 256
#define BN 256
#define BK 64
#define NKT (FIN/BK)           // 16 K-tiles

typedef float fx4 __attribute__((ext_vector_type(4)));
typedef short sv8 __attribute__((ext_vector_type(8)));   // 8 bf16 (MFMA frag)

union BCvt { sv8 s; __bf16 b[8]; };

__device__ __forceinline__ unsigned short bfbits(float f) {
    union { __bf16 b; unsigned short u; } c; c.b = (__bf16)f; return c.u;
}
__device__ __forceinline__ sv8 cvt8(fx4 lo, fx4 hi) {
    BCvt u;
#pragma unroll
    for (int i = 0; i < 4; ++i) { u.b[i] = (__bf16)lo[i]; u.b[i + 4] = (__bf16)hi[i]; }
    return u.s;
}

// ---------------------------------------------------------------------------
// Prepass: W [P][K][N] fp32 -> Wt tiled+swizzled bf16 (16.8 MB in d_ws).
// Tile (p, nt, kt) = contiguous 32 KB LDS image of B[256 n][64 k]:
//   byte_in_tile = n*128 + ((kg*16) ^ ((n&7)<<4)), kg = k/8
// ---------------------------------------------------------------------------
__global__ __launch_bounds__(256) void wtrans(const float* __restrict__ w,
                                              unsigned short* __restrict__ wt) {
    __shared__ unsigned short L[64][260];
    const int bid = blockIdx.x;              // 8*4*16 = 512 blocks
    const int p  = bid >> 6;
    const int nt = (bid >> 4) & 3;
    const int kt = bid & 15;
    const int k0 = kt * 64, n0 = nt * 256;
    const int t = threadIdx.x;

    const int nf = t & 63, kseg = t >> 6;
#pragma unroll
    for (int rr = 0; rr < 16; ++rr) {
        const int k = kseg * 16 + rr;
        fx4 v = *(const fx4*)(w + (size_t)p * (FIN*FOUT) + (size_t)(k0 + k) * FOUT + n0 + nf * 4);
        L[k][nf*4+0] = bfbits(v[0]); L[k][nf*4+1] = bfbits(v[1]);
        L[k][nf*4+2] = bfbits(v[2]); L[k][nf*4+3] = bfbits(v[3]);
    }
    __syncthreads();

    unsigned short* tile = wt + (size_t)((p * 4 + nt) * 16 + kt) * 16384;
    const int n = t;  // 0..255
#pragma unroll
    for (int kg = 0; kg < 8; ++kg) {
        union { sv8 s; unsigned short us[8]; } u;
#pragma unroll
        for (int e = 0; e < 8; ++e) u.us[e] = L[kg * 8 + e][n];
        const int byte_ = n * 128 + ((kg * 16) ^ ((n & 7) << 4));
        *(sv8*)((char*)tile + byte_) = u.s;
    }
}

// ---------------------------------------------------------------------------
// 256x256 grouped GEMM, counted-vmcnt double-buffered pipeline.
// ---------------------------------------------------------------------------
#define STR2(x) #x
// wait: retire all but N youngest vmem ops, all LDS ops; then barrier
#define VMBAR(N) do {                                                          \
    asm volatile("s_waitcnt vmcnt(" STR2(N) ") lgkmcnt(0)" ::: "memory");      \
    __builtin_amdgcn_s_barrier();                                              \
} while (0)
#define MEMFENCE asm volatile("" ::: "memory")

// A loads: thread covers rows {mrow, mrow+128}, k-chunk kg4*16 (8 x dwordx4)
#define LOADA(kt) do {                                                         \
    _Pragma("unroll")                                                          \
    for (int rr = 0; rr < 2; ++rr) {                                           \
        const float* s_ = aptr + (size_t)rr * (128 * ROWSTRIDE) + (kt) * BK;   \
        _Pragma("unroll")                                                      \
        for (int i = 0; i < 4; ++i) rA[rr*4+i] = *(const fx4*)(s_ + i * 4);    \
    }                                                                          \
} while (0)

// cvt rA -> swizzled LDS image (4 x ds_write_b128)
#define STOREA(dst) do {                                                       \
    _Pragma("unroll")                                                          \
    for (int rr = 0; rr < 2; ++rr) {                                           \
        const int row_ = mrow + rr * 128;                                      \
        char* bp = (dst) + row_ * 128;                                         \
        const int sw = (row_ & 7) << 4;                                        \
        *(sv8*)(bp + ((kg4 * 32)      ^ sw)) = cvt8(rA[rr*4+0], rA[rr*4+1]);   \
        *(sv8*)(bp + ((kg4 * 32 + 16) ^ sw)) = cvt8(rA[rr*4+2], rA[rr*4+3]);   \
    }                                                                          \
} while (0)

// B: 32 KB tile via 4 x global_load_lds width-16 (pre-swizzled source)
#define GLOADB(kt, dst) do {                                                   \
    const char* gb_ = (const char*)btile + (size_t)(kt) * 32768;               \
    _Pragma("unroll")                                                          \
    for (int c_ = 0; c_ < 4; ++c_) {                                           \
        __builtin_amdgcn_global_load_lds(                                      \
            (const __attribute__((address_space(1))) void*)(gb_ + c_ * 8192 + tid * 16), \
            (__attribute__((address_space(3))) void*)((dst) + c_ * 8192 + tid * 16),     \
            16, 0, 0);                                                         \
    }                                                                          \
} while (0)

#define READ_A(srcb, mh) do {                                                  \
    _Pragma("unroll")                                                          \
    for (int i = 0; i < 4; ++i) {                                              \
        const int row_ = wm * 128 + (mh) * 64 + i * 16 + (lane & 15);          \
        const char* bp = (srcb) + row_ * 128;                                  \
        const int sw = (row_ & 7) << 4;                                        \
        _Pragma("unroll")                                                      \
        for (int ks = 0; ks < 2; ++ks)                                         \
            af[i][ks] = *(const sv8*)(bp + ((ks * 64 + (lane >> 4) * 16) ^ sw)); \
    }                                                                          \
} while (0)

#define READ_B(srcb, nh, dst) do {                                             \
    _Pragma("unroll")                                                          \
    for (int j = 0; j < 2; ++j) {                                              \
        const int row_ = wn * 64 + (nh) * 32 + j * 16 + (lane & 15);           \
        const char* bp = (srcb) + row_ * 128;                                  \
        const int sw = (row_ & 7) << 4;                                        \
        _Pragma("unroll")                                                      \
        for (int ks = 0; ks < 2; ++ks)                                         \
            dst[j][ks] = *(const sv8*)(bp + ((ks * 64 + (lane >> 4) * 16) ^ sw)); \
    }                                                                          \
} while (0)

#define MFMA_Q(mh, nh, bfr) do {                                               \
    __builtin_amdgcn_s_setprio(1);                                             \
    _Pragma("unroll")                                                          \
    for (int i = 0; i < 4; ++i)                                                \
        _Pragma("unroll")                                                      \
        for (int j = 0; j < 2; ++j)                                            \
            _Pragma("unroll")                                                  \
            for (int ks = 0; ks < 2; ++ks)                                     \
                acc[(mh)*4+i][(nh)*2+j] = __builtin_amdgcn_mfma_f32_16x16x32_bf16( \
                    af[i][ks], bfr[j][ks], acc[(mh)*4+i][(nh)*2+j], 0, 0, 0);  \
    __builtin_amdgcn_s_setprio(0);                                             \
} while (0)

__global__ __launch_bounds__(512, 1)
void pd_gemm(const float* __restrict__ x, const unsigned short* __restrict__ wt,
             const float* __restrict__ bias, float* __restrict__ out) {
    __shared__ __align__(16) char ldsA0[BM * BK * 2];   // 32 KB each
    __shared__ __align__(16) char ldsA1[BM * BK * 2];
    __shared__ __align__(16) char ldsB0[BN * BK * 2];
    __shared__ __align__(16) char ldsB1[BN * BK * 2];

    const int tid = threadIdx.x;
    const int lane = tid & 63;
    const int wv = tid >> 6;            // 8 waves: 2(m) x 4(n)
    const int wm = wv >> 2, wn = wv & 3;

    // 1024 blocks; p == XCD (128 blocks per p); n fastest within p
    const int bid = blockIdx.x;
    const int p   = bid & 7;
    const int wrk = bid >> 3;           // 0..127
    const int n0  = (wrk & 3) * BN;
    const int m0  = (wrk >> 2) * BM;

    const int kg4 = tid & 3, mrow = tid >> 2;   // A staging map
    const float* aptr = x + (size_t)(m0 + mrow) * ROWSTRIDE + p * FIN + kg4 * 16;
    const unsigned short* btile = wt + (size_t)((p * 4 + (n0 >> 8)) * 16) * 16384;

    fx4 acc[8][4];
#pragma unroll
    for (int i = 0; i < 8; ++i)
#pragma unroll
        for (int j = 0; j < 4; ++j) acc[i][j] = (fx4)0.0f;

    fx4 rA[8];
    sv8 af[4][2], bf0[2][2], bf1[2][2];

    // Prologue: stage tile0 fully; issue A(1); pipeline invariant at entry:
    //   cur buf staged; rA holds A(t+1) in flight (8 loads outstanding)
    LOADA(0);
    GLOADB(0, ldsB0);
    STOREA(ldsA0);            // auto-waits the A(0) loads only
    MEMFENCE;
    LOADA(1);
    VMBAR(8);                 // retire gloadB(0); A(1) stays in flight

#pragma unroll 1
    for (int kk = 0; kk < 7; ++kk) {
        const int t = 2 * kk;
        // tile t (cur=0, nxt=1)
        READ_A(ldsA0, 0); READ_B(ldsB0, 0, bf0); MFMA_Q(0, 0, bf0);
        READ_B(ldsB0, 1, bf1); MFMA_Q(0, 1, bf1);
        STOREA(ldsA1);                    // A(t+1) -> nxt
        GLOADB(t + 1, ldsB1);
        READ_A(ldsA0, 1); MFMA_Q(1, 0, bf0); MFMA_Q(1, 1, bf1);
        MEMFENCE;
        LOADA(t + 2);                     // A(t+2) -> rA (younger than gloadB)
        VMBAR(8);                         // retire gloadB(t+1); keep A(t+2)
        // tile t+1 (cur=1, nxt=0)
        READ_A(ldsA1, 0); READ_B(ldsB1, 0, bf0); MFMA_Q(0, 0, bf0);
        READ_B(ldsB1, 1, bf1); MFMA_Q(0, 1, bf1);
        STOREA(ldsA0);
        GLOADB(t + 2, ldsB0);
        READ_A(ldsA1, 1); MFMA_Q(1, 0, bf0); MFMA_Q(1, 1, bf1);
        MEMFENCE;
        LOADA(t + 3);
        VMBAR(8);
    }
    // t = 14 (cur=0, nxt=1): stage tile 15, no further prefetch
    READ_A(ldsA0, 0); READ_B(ldsB0, 0, bf0); MFMA_Q(0, 0, bf0);
    READ_B(ldsB0, 1, bf1); MFMA_Q(0, 1, bf1);
    STOREA(ldsA1);
    GLOADB(15, ldsB1);
    READ_A(ldsA0, 1); MFMA_Q(1, 0, bf0); MFMA_Q(1, 1, bf1);
    VMBAR(0);                             // drain once: tile 15 fully staged
    // t = 15 (cur=1)
    READ_A(ldsA1, 0); READ_B(ldsB1, 0, bf0); MFMA_Q(0, 0, bf0);
    READ_B(ldsB1, 1, bf1); MFMA_Q(0, 1, bf1);
    READ_A(ldsA1, 1); MFMA_Q(1, 0, bf0); MFMA_Q(1, 1, bf1);

    // Epilogue: C/D map col = lane&15, row = (lane>>4)*4 + j
    const float* bs = bias + p * FOUT;
#pragma unroll
    for (int nf = 0; nf < 4; ++nf) {
        const int col = n0 + wn * 64 + nf * 16 + (lane & 15);
        const float bv = bs[col];
#pragma unroll
        for (int mf = 0; mf < 8; ++mf) {
            const int row = m0 + wm * 128 + mf * 16 + (lane >> 4) * 4;
            float* o = out + (size_t)row * OROWSTRIDE + p * FOUT + col;
#pragma unroll
            for (int j = 0; j < 4; ++j)
                o[j * OROWSTRIDE] = acc[mf][nf][j] + bv;
        }
    }
}

// Fallback if d_ws can't hold Wt (never observed): correct but slow.
__global__ __launch_bounds__(256) void pd_naive(const float* __restrict__ x,
                                                const float* __restrict__ w,
                                                const float* __restrict__ bias,
                                                float* __restrict__ out) {
    const long long total = (long long)MROWS * PP * FOUT;
    for (long long idx = blockIdx.x * 256LL + threadIdx.x; idx < total;
         idx += (long long)gridDim.x * 256) {
        const int n = (int)(idx & 1023);
        const int p = (int)((idx >> 10) & 7);
        const long long m = idx >> 13;
        const float* xr = x + m * ROWSTRIDE + p * FIN;
        const float* wc = w + (size_t)p * (FIN*FOUT) + n;
        float s = bias[p * FOUT + n];
        for (int k = 0; k < FIN; ++k) s += xr[k] * wc[(size_t)k * FOUT];
        out[idx] = s;
    }
}

extern "C" void kernel_launch(void* const* d_in, const int* in_sizes, int n_in,
                              void* d_out, int out_size, void* d_ws, size_t ws_size,
                              hipStream_t stream) {
    const float* x    = (const float*)d_in[0];
    const float* w    = (const float*)d_in[1];
    const float* bias = (const float*)d_in[2];
    float* out = (float*)d_out;

    const size_t WT_BYTES = (size_t)PP * FIN * FOUT * sizeof(unsigned short);  // 16.8 MB
    if (ws_size >= WT_BYTES) {
        unsigned short* wt = (unsigned short*)d_ws;
        wtrans<<<dim3(512), dim3(256), 0, stream>>>(w, wt);
        const int nblk = PP * (MROWS / BM) * (FOUT / BN);   // 8*32*4 = 1024
        pd_gemm<<<dim3(nblk), dim3(512), 0, stream>>>(x, wt, bias, out);
    } else {
        pd_naive<<<dim3(2048), dim3(256), 0, stream>>>(x, w, bias, out);
    }
}